// Round 14
// baseline (1062.213 us; speedup 1.0000x reference)
//
#include <hip/hip_runtime.h>
#include <hip/hip_bf16.h>

#define T_TOK 8192
#define DDIM 1024
#define HDIM 4096

typedef __bf16 bf16;
typedef bf16 bf16x8 __attribute__((ext_vector_type(8)));
typedef float f32x4 __attribute__((ext_vector_type(4)));

#define ASM_VMCNT(n) asm volatile("s_waitcnt vmcnt(" #n ")" ::: "memory")
#define MFMA16(a, b, c) __builtin_amdgcn_mfma_f32_16x16x32_bf16((a), (b), (c), 0, 0, 0)
#define G8_BAR __builtin_amdgcn_s_barrier()
#define G8_WAIT                                            \
  asm volatile("s_waitcnt lgkmcnt(0)" ::: "memory");       \
  __builtin_amdgcn_sched_barrier(0)

__device__ __forceinline__ void gl_lds16(const void* g, void* l) {
  __builtin_amdgcn_global_load_lds(
      (const __attribute__((address_space(1))) unsigned int*)g,
      (__attribute__((address_space(3))) unsigned int*)l, 16, 0, 0);
}

// Fast exact-grade GELU: erf via A&S 7.1.26 (|err|<=1.5e-7 << bf16 rounding).
__device__ __forceinline__ float gelu_f(float v) {
  const float x = v * 0.7071067811865475f;
  const float ax = fabsf(x);
  const float t = 1.0f / fmaf(0.3275911f, ax, 1.0f);
  float p = fmaf(1.061405429f, t, -1.453152027f);
  p = fmaf(p, t, 1.421413741f);
  p = fmaf(p, t, -0.284496736f);
  p = fmaf(p, t, 0.254829592f);
  p = p * t;
  const float e = __expf(-ax * ax);
  const float er = fmaf(-p, e, 1.0f);
  const float erfx = (x >= 0.0f) ? er : -er;
  return 0.5f * v * (1.0f + erfx);
}

// ---------- fused: x fp32 -> bf16 convert + router probs/top2 ----------
__global__ __launch_bounds__(256) void conv_router(
    const float* __restrict__ x, bf16* __restrict__ xb,
    const float* __restrict__ srw, const float* __restrict__ srb,
    const float* __restrict__ hrw, const float* __restrict__ hrb,
    float* __restrict__ gate, float4* __restrict__ probs4,
    int* __restrict__ top2) {
  const int lane = threadIdx.x & 63;
  const int w = threadIdx.x >> 6;
  const int t = blockIdx.x * 4 + w;

  const float* xr = x + (size_t)t * DDIM;
  bf16* xbr = xb + (size_t)t * DDIM;
  float p0 = 0, p1 = 0, p2 = 0, p3 = 0, p4 = 0, p5 = 0;
#pragma unroll
  for (int c = 0; c < 4; ++c) {
    const int d = c * 256 + lane * 4;
    const float4 xv = *(const float4*)(xr + d);
    bf16 ov[4] = {(bf16)xv.x, (bf16)xv.y, (bf16)xv.z, (bf16)xv.w};
    *(float2*)(xbr + d) = *(float2*)ov;
    const float xa[4] = {xv.x, xv.y, xv.z, xv.w};
#pragma unroll
    for (int j = 0; j < 4; ++j) {
      const float xd = xa[j];
      const float4 r4 = *(const float4*)(srw + (size_t)(d + j) * 4);
      p0 += xd * r4.x; p1 += xd * r4.y; p2 += xd * r4.z; p3 += xd * r4.w;
      const float2 r2 = *(const float2*)(hrw + (size_t)(d + j) * 2);
      p4 += xd * r2.x; p5 += xd * r2.y;
    }
  }
#pragma unroll
  for (int off = 32; off >= 1; off >>= 1) {
    p0 += __shfl_xor(p0, off);
    p1 += __shfl_xor(p1, off);
    p2 += __shfl_xor(p2, off);
    p3 += __shfl_xor(p3, off);
    p4 += __shfl_xor(p4, off);
    p5 += __shfl_xor(p5, off);
  }
  if (lane == 0) {
    const float l0 = p0 + srb[0], l1 = p1 + srb[1];
    const float l2 = p2 + srb[2], l3 = p3 + srb[3];
    const float m = fmaxf(fmaxf(l0, l1), fmaxf(l2, l3));
    const float e0 = expf(l0 - m), e1 = expf(l1 - m);
    const float e2 = expf(l2 - m), e3 = expf(l3 - m);
    const float s = e0 + e1 + e2 + e3;
    float pr[4] = {e0 / s, e1 / s, e2 / s, e3 / s};
    int i1 = 0; float v1 = pr[0];
#pragma unroll
    for (int e = 1; e < 4; ++e) if (pr[e] > v1) { v1 = pr[e]; i1 = e; }
    int i2 = -1; float v2 = -1.0f;
#pragma unroll
    for (int e = 0; e < 4; ++e)
      if (e != i1 && pr[e] > v2) { v2 = pr[e]; i2 = e; }
    float g[4] = {0, 0, 0, 0};
    g[i1] = v1; g[i2] = v2;
    float* gr = gate + (size_t)t * 8;
    gr[0] = g[0]; gr[1] = g[1]; gr[2] = g[2]; gr[3] = g[3];
    const float h0 = p4 + hrb[0], h1 = p5 + hrb[1];
    const float mh = fmaxf(h0, h1);
    const float q0 = expf(h0 - mh), q1 = expf(h1 - mh);
    const float qs = q0 + q1;
    gr[4] = q0 / qs; gr[5] = q1 / qs; gr[6] = 0; gr[7] = 0;
    probs4[t] = make_float4(pr[0], pr[1], pr[2], pr[3]);
    top2[t] = i1 | (i2 << 8);
  }
}

// ---- weight transpose+convert, 6 experts per dispatch (z: 0-3 spec, 4-5 shr)
__global__ __launch_bounds__(256) void transpose_convert6(
    const float* __restrict__ spec_w, const float* __restrict__ shr_w,
    bf16* __restrict__ dst, int R, int C) {
  __shared__ float tile[32][33];
  const int z = blockIdx.z;
  const float* src = (z < 4) ? spec_w + (size_t)z * R * C
                             : shr_w + (size_t)(z - 4) * R * C;
  bf16* d = dst + (size_t)z * R * C;
  const int c0 = blockIdx.x * 32, r0 = blockIdx.y * 32;
  const int tx = threadIdx.x & 31, ty = threadIdx.x >> 5;
#pragma unroll
  for (int i = 0; i < 4; ++i)
    tile[ty + 8 * i][tx] = src[(size_t)(r0 + ty + 8 * i) * C + c0 + tx];
  __syncthreads();
#pragma unroll
  for (int i = 0; i < 4; ++i)
    d[(size_t)(c0 + ty + 8 * i) * R + r0 + tx] = (bf16)tile[tx][ty + 8 * i];
}

// ---------------- router pass 2: scan -> lists / tpos / meta / aux ----------
// meta[24..27] spec counts; meta[34..37] packed h row base per spec expert;
// meta[40..44] spec-g1 block prefix (64*ch); meta[46..50] spec-g2 prefix (32*ch)
__global__ __launch_bounds__(1024) void scan_build(
    const int* __restrict__ top2, const float4* __restrict__ probs4,
    int* __restrict__ meta, int* __restrict__ lists, int2* __restrict__ tpos,
    float* __restrict__ auxg) {
  __shared__ unsigned long long sc[1024];
  __shared__ float4 rp[512];
  const int tid = threadIdx.x;

  int ee[8];
  unsigned long long c = 0;
  float4 ps = make_float4(0.f, 0.f, 0.f, 0.f);
#pragma unroll
  for (int j = 0; j < 8; ++j) {
    const int t = tid * 8 + j;
    const int p = top2[t];
    ee[j] = p;
    const int a = p & 15, b = (p >> 8) & 15;
    c += (1ULL << (16 * a)) + (1ULL << (16 * b));
    const float4 pv = probs4[t];
    ps.x += pv.x; ps.y += pv.y; ps.z += pv.z; ps.w += pv.w;
  }
  sc[tid] = c;
  __syncthreads();
  for (int off = 1; off < 1024; off <<= 1) {
    const unsigned long long mine = sc[tid];
    const unsigned long long prev = (tid >= off) ? sc[tid - off] : 0ULL;
    __syncthreads();
    sc[tid] = mine + prev;
    __syncthreads();
  }
  const unsigned long long incl = sc[tid];
  const unsigned long long tot = sc[1023];
  const unsigned long long excl = incl - c;
  int q0 = (int)(excl & 0xffff), q1 = (int)((excl >> 16) & 0xffff);
  int q2 = (int)((excl >> 32) & 0xffff), q3 = (int)((excl >> 48) & 0xffff);
#pragma unroll
  for (int j = 0; j < 8; ++j) {
    const int t = tid * 8 + j;
    const int a = ee[j] & 15, b = (ee[j] >> 8) & 15;
    const int pa = (a == 0) ? q0 : (a == 1) ? q1 : (a == 2) ? q2 : q3;
    lists[a * 8192 + pa] = t;
    q0 += (a == 0); q1 += (a == 1); q2 += (a == 2); q3 += (a == 3);
    const int pb = (b == 0) ? q0 : (b == 1) ? q1 : (b == 2) ? q2 : q3;
    lists[b * 8192 + pb] = t;
    q0 += (b == 0); q1 += (b == 1); q2 += (b == 2); q3 += (b == 3);
    tpos[t] = make_int2(a * 8192 + pa, b * 8192 + pb);
  }
  if (tid == 1023) {
    const int c0 = (int)(tot & 0xffff), c1 = (int)((tot >> 16) & 0xffff);
    const int c2 = (int)((tot >> 32) & 0xffff), c3 = (int)((tot >> 48) & 0xffff);
    meta[24] = c0; meta[25] = c1; meta[26] = c2; meta[27] = c3;
    auxg[0] = (float)c0; auxg[1] = (float)c1;
    auxg[2] = (float)c2; auxg[3] = (float)c3;
    const int nb0 = (c0 + 255) >> 8, nb1 = (c1 + 255) >> 8;
    const int nb2 = (c2 + 255) >> 8, nb3 = (c3 + 255) >> 8;
    const int ch0 = (nb0 + 3) >> 2, ch1 = (nb1 + 3) >> 2;
    const int ch2 = (nb2 + 3) >> 2, ch3 = (nb3 + 3) >> 2;
    meta[34] = 0;
    meta[35] = nb0 * 256;
    meta[36] = meta[35] + nb1 * 256;
    meta[37] = meta[36] + nb2 * 256;
    meta[40] = 0;
    meta[41] = 64 * ch0;
    meta[42] = meta[41] + 64 * ch1;
    meta[43] = meta[42] + 64 * ch2;
    meta[44] = meta[43] + 64 * ch3;
    meta[46] = 0;
    meta[47] = 32 * ch0;
    meta[48] = meta[47] + 32 * ch1;
    meta[49] = meta[48] + 32 * ch2;
    meta[50] = meta[49] + 32 * ch3;
  }
  if (tid >= 512) rp[tid - 512] = ps;
  __syncthreads();
  if (tid < 512) {
    const float4 o = rp[tid];
    ps.x += o.x; ps.y += o.y; ps.z += o.z; ps.w += o.w;
  }
  for (int w = 256; w >= 1; w >>= 1) {
    __syncthreads();
    if (tid >= w && tid < 2 * w) rp[tid - w] = ps;
    __syncthreads();
    if (tid < w) {
      const float4 o = rp[tid];
      ps.x += o.x; ps.y += o.y; ps.z += o.z; ps.w += o.w;
    }
  }
  if (tid == 0) {
    auxg[4] = ps.x; auxg[5] = ps.y; auxg[6] = ps.z; auxg[7] = ps.w;
  }
}

__global__ void aux_finalize(const float* __restrict__ auxg,
                             float* __restrict__ outp) {
  float a = 0.0f;
#pragma unroll
  for (int e = 0; e < 4; ++e)
    a += (auxg[e] / (float)(T_TOK * 2)) * (auxg[4 + e] / (float)T_TOK);
  outp[0] = 4.0f * a;
}

// ---------------- g8: 8-phase 256x256 GEMM1  h = gate * gelu(A*B^T + b1) ----
// KIND 0: dense rows, merged shared N=8192 (per-block expert = 4 + (bn>>4)).
// KIND 1: spec batched (segments via meta[40..44], packed hb = meta[34+s],
//         gate = gate[tok*8+s], tok<0 -> 0).
template <int KIND>
__global__ __launch_bounds__(512, 2) void g8(
    const bf16* __restrict__ A, const bf16* __restrict__ Bw,
    const float* __restrict__ bias, bf16* __restrict__ h_all, int N,
    int CH_M, int CH_N, const int* __restrict__ meta,
    const int* __restrict__ lists, const float* __restrict__ gate) {
  __shared__ __align__(1024) bf16 Alds[2 * 256 * 64];
  __shared__ __align__(1024) bf16 Blds[2 * 256 * 64];

  const int tid = threadIdx.x;
  const int lane = tid & 63, wid = tid >> 6;
  const int wm = wid >> 2, wn = wid & 3;
  const int lr = lane & 15, lg = lane >> 4;

  int bm, bn, hb = 0, s = 0;
  const bf16* Bp = Bw;
  const float* biasp = bias;
  if constexpr (KIND == 0) {
    const int xcd = blockIdx.x & 7, idx = blockIdx.x >> 3;
    bm = (xcd >> 1) * CH_M + idx / CH_N;
    bn = (xcd & 1) * CH_N + idx % CH_N;
  } else {
    const int b = blockIdx.x;
    if (b >= meta[44]) return;
    s = (b >= meta[41]) + (b >= meta[42]) + (b >= meta[43]);
    const int local = b - meta[40 + s];
    const int nbm = (meta[24 + s] + 255) >> 8;
    const int CHm = (nbm + 3) >> 2;
    if (local >= 64 * CHm) return;
    const int xc = local & 7, idx = local >> 3;
    bm = (xc >> 1) * CHm + idx / 8;
    bn = (xc & 1) * 8 + idx % 8;
    if (bm >= nbm) return;
    hb = meta[34 + s];
    Bp = Bw + (size_t)s * DDIM * HDIM;
    biasp = bias + (size_t)s * HDIM;
  }
  const int K = DDIM;
  const int NT = K >> 6;  // 16

  // ---- staging: thread covers 16B of an 8KB chunk (64 rows x 128B) ----
  const int rl = tid >> 3;
  const int cbs = ((tid * 16) & 127) ^ ((rl & 7) << 4);
  int ar[4];
#pragma unroll
  for (int c = 0; c < 4; ++c) ar[c] = bm * 256 + c * 64 + rl;
  if constexpr (KIND != 0) {
    const int* lp = lists + s * 8192;
#pragma unroll
    for (int c = 0; c < 4; ++c) {
      const int t = lp[ar[c]];
      ar[c] = t < 0 ? 0 : t;
    }
  }
  const bf16* sA[4];
  const bf16* sB[4];
#pragma unroll
  for (int c = 0; c < 4; ++c) {
    sA[c] = A + (size_t)ar[c] * K + (cbs >> 1);
    sB[c] = Bp + (size_t)(bn * 256 + c * 64 + rl) * K + (cbs >> 1);
  }
  char* const ldsA = (char*)Alds;
  char* const ldsB = (char*)Blds;
  const int wb = wid * 1024;

  const int ax0 = (lg * 16) ^ ((lr & 7) << 4);
  const int ax1 = ax0 ^ 64;
  const int aro = (wm * 128 + lr) * 128;
  const int bro = (wn * 64 + lr) * 128;
  const char* const A0 = (const char*)Alds + aro + ax0;
  const char* const A1 = (const char*)Alds + aro + ax1;
  const char* const B0 = (const char*)Blds + bro + ax0;
  const char* const B1 = (const char*)Blds + bro + ax1;

  f32x4 acc[8][4] = {};
  bf16x8 af[4][2], b01[2][2], b23[2][2];

#define G8_RA(BOFF, MB)                                               \
  _Pragma("unroll") for (int i = 0; i < 4; ++i) {                     \
    af[i][0] = *(const bf16x8*)(A0 + (BOFF) + ((MB) + i) * 2048);     \
    af[i][1] = *(const bf16x8*)(A1 + (BOFF) + ((MB) + i) * 2048);     \
  }
#define G8_RB(BOFF, DST, NB)                                          \
  _Pragma("unroll") for (int i = 0; i < 2; ++i) {                     \
    DST[i][0] = *(const bf16x8*)(B0 + (BOFF) + ((NB) + i) * 2048);    \
    DST[i][1] = *(const bf16x8*)(B1 + (BOFF) + ((NB) + i) * 2048);    \
  }
#define G8_MMA(MB, NB, BSRC)                                          \
  __builtin_amdgcn_s_setprio(1);                                      \
  _Pragma("unroll") for (int i = 0; i < 4; ++i)                       \
    _Pragma("unroll") for (int j = 0; j < 2; ++j) {                   \
      acc[(MB) + i][(NB) + j] =                                       \
          MFMA16(af[i][0], BSRC[j][0], acc[(MB) + i][(NB) + j]);      \
      acc[(MB) + i][(NB) + j] =                                       \
          MFMA16(af[i][1], BSRC[j][1], acc[(MB) + i][(NB) + j]);      \
    }                                                                 \
  __builtin_amdgcn_s_setprio(0);
#define G8_STG_B(T, C, BUFO)                                          \
  gl_lds16(sB[C] + (size_t)(T) * 64, ldsB + (BUFO) + (C) * 8192 + wb);
#define G8_STG_A(T, C, BUFO)                                          \
  gl_lds16(sA[C] + (size_t)(T) * 64, ldsA + (BUFO) + (C) * 8192 + wb);

  G8_STG_B(0, 0, 0) G8_STG_B(0, 1, 0) G8_STG_B(0, 2, 0) G8_STG_B(0, 3, 0)
  G8_STG_A(0, 0, 0) G8_STG_A(0, 1, 0) G8_STG_A(0, 2, 0) G8_STG_A(0, 3, 0)
  G8_STG_B(1, 0, 32768) G8_STG_B(1, 1, 32768)
  G8_STG_B(1, 2, 32768) G8_STG_B(1, 3, 32768)
  G8_STG_A(1, 0, 32768) G8_STG_A(1, 1, 32768)
  G8_STG_A(1, 2, 32768) G8_STG_A(1, 3, 32768)
  ASM_VMCNT(8);
  G8_BAR;

  for (int t = 0; t < NT; t += 2) {
    const bool stg = (t + 2) < NT;
    G8_RA(0, 0);
    G8_RB(0, b01, 0);
    G8_BAR; G8_WAIT;
    G8_MMA(0, 0, b01);
    G8_BAR;
    G8_RB(0, b23, 2);
    G8_BAR; G8_WAIT;
    G8_MMA(0, 2, b23);
    G8_BAR;
    G8_RA(0, 4);
    if (stg) { G8_STG_B(t + 2, 0, 0) G8_STG_B(t + 2, 1, 0) }
    G8_BAR; G8_WAIT;
    G8_MMA(4, 0, b01);
    G8_BAR;
    if (stg) { G8_STG_B(t + 2, 2, 0) G8_STG_B(t + 2, 3, 0) }
    G8_MMA(4, 2, b23);
    if (stg) ASM_VMCNT(4); else ASM_VMCNT(0);
    G8_BAR;
    G8_RA(32768, 0);
    G8_RB(32768, b01, 0);
    if (stg) { G8_STG_A(t + 2, 0, 0) G8_STG_A(t + 2, 1, 0) }
    G8_BAR; G8_WAIT;
    G8_MMA(0, 0, b01);
    G8_BAR;
    G8_RB(32768, b23, 2);
    if (stg) { G8_STG_A(t + 2, 2, 0) G8_STG_A(t + 2, 3, 0) }
    G8_BAR; G8_WAIT;
    G8_MMA(0, 2, b23);
    G8_BAR;
    G8_RA(32768, 4);
    if (stg) {
      G8_STG_B(t + 3, 0, 32768) G8_STG_B(t + 3, 1, 32768)
      G8_STG_B(t + 3, 2, 32768) G8_STG_B(t + 3, 3, 32768)
    }
    G8_BAR; G8_WAIT;
    G8_MMA(4, 0, b01);
    G8_BAR;
    if (stg) {
      G8_STG_A(t + 3, 0, 32768) G8_STG_A(t + 3, 1, 32768)
      G8_STG_A(t + 3, 2, 32768) G8_STG_A(t + 3, 3, 32768)
    }
    G8_MMA(4, 2, b23);
    if (stg) ASM_VMCNT(8);
    G8_BAR;
  }

  // ---- epilogue: h = gate * gelu(acc + bias) ----
  const int colb = bn * 256 + wn * 64;
  const int rowb = bm * 256 + wm * 128 + lg * 4;
  float bv[4];
#pragma unroll
  for (int nf = 0; nf < 4; ++nf) bv[nf] = biasp[colb + nf * 16 + lr];
  const int sgid = (KIND == 0) ? 4 + (bn >> 4) : s;  // shared: col-half expert
#pragma unroll
  for (int mf = 0; mf < 8; ++mf) {
    float gv[4];
#pragma unroll
    for (int r = 0; r < 4; ++r) {
      const int lrow = rowb + mf * 16 + r;
      if constexpr (KIND == 0) {
        gv[r] = gate[(size_t)lrow * 8 + sgid];
      } else {
        const int tok = lists[s * 8192 + lrow];
        gv[r] = tok >= 0 ? gate[(size_t)tok * 8 + sgid] : 0.0f;
      }
    }
#pragma unroll
    for (int nf = 0; nf < 4; ++nf) {
      const int col = colb + nf * 16 + lr;
#pragma unroll
      for (int r = 0; r < 4; ++r) {
        const int row = hb + rowb + mf * 16 + r;
        h_all[(size_t)row * N + col] =
            (bf16)(gv[r] * gelu_f(acc[mf][nf][r] + bv[nf]));
      }
    }
  }
}

// ---------------- g2sh: merged shared GEMM2, K=8192, '=' --------------------
// out[t] = h_shr[t]*[W2_0;W2_1]^T + g4*b2_0 + g5*b2_1  (h gate-folded)
__global__ __launch_bounds__(512, 2) void g2sh(
    const bf16* __restrict__ A, const bf16* __restrict__ w2_0,
    const bf16* __restrict__ w2_1, const float* __restrict__ b2,
    float* __restrict__ out, const float* __restrict__ gate) {
  __shared__ __align__(1024) bf16 Alds[2 * 256 * 64];
  __shared__ __align__(1024) bf16 Blds[2 * 128 * 64];

  const int tid = threadIdx.x;
  const int lane = tid & 63, wid = tid >> 6;
  const int wm = wid >> 2, wn = wid & 3;
  const int lr = lane & 15, lg = lane >> 4;

  const int xcd = blockIdx.x & 7, idx = blockIdx.x >> 3;
  const int bm = (xcd >> 1) * 8 + idx / 4;
  const int bn = (xcd & 1) * 4 + idx % 4;
  const int lda = 8192, N = DDIM;
  const int NT = 128;

  const int L = tid * 16;
  const int rl = L >> 7;
  const int colb = (L & 127) ^ ((rl & 7) << 4);

  const int ar0 = bm * 256 + rl;
  const bf16* sAc0 = A + (size_t)ar0 * lda + (colb >> 1);
  const bf16* sAc1 = A + (size_t)(ar0 + 64) * lda + (colb >> 1);
  const bf16* sAc2 = A + (size_t)(ar0 + 128) * lda + (colb >> 1);
  const bf16* sAc3 = A + (size_t)(ar0 + 192) * lda + (colb >> 1);
  // B halves: rows stride 4096 within each expert's W2
  const bf16* pB[2][2];
  pB[0][0] = w2_0 + (size_t)(bn * 128 + rl) * 4096 + (colb >> 1);
  pB[0][1] = w2_0 + (size_t)(bn * 128 + 64 + rl) * 4096 + (colb >> 1);
  pB[1][0] = w2_1 + (size_t)(bn * 128 + rl) * 4096 + (colb >> 1);
  pB[1][1] = w2_1 + (size_t)(bn * 128 + 64 + rl) * 4096 + (colb >> 1);

  char* const ldsA = (char*)Alds;
  char* const ldsB = (char*)Blds;
  const int wb = wid * 1024;
  char* const stA[2] = {ldsA + wb, ldsA + 32768 + wb};
  char* const stB[2] = {ldsB + wb, ldsB + 16384 + wb};

  const int ax0 = (lg * 16) ^ ((lr & 7) << 4);
  const int ax1 = ax0 ^ 64;
  const int aro = (wm * 128 + lr) * 128;
  const int bro = (wn * 32 + lr) * 128;
  const char* const Ak0[2] = {ldsA + aro + ax0, ldsA + 32768 + aro + ax0};
  const char* const Ak1[2] = {ldsA + aro + ax1, ldsA + 32768 + aro + ax1};
  const char* const Bk0[2] = {ldsB + bro + ax0, ldsB + 16384 + bro + ax0};
  const char* const Bk1[2] = {ldsB + bro + ax1, ldsB + 16384 + bro + ax1};

  f32x4 acc[8][2] = {};

#define G2S_STB(T, DST)                                                   \
  {                                                                       \
    const int hh = (T) >> 6;                                              \
    const size_t oo = (size_t)((T) & 63) * 64;                            \
    gl_lds16(pB[hh][0] + oo, DST);                                        \
    gl_lds16(pB[hh][1] + oo, DST + 8192);                                 \
  }

  gl_lds16(sAc0, stA[0]);
  gl_lds16(sAc1, stA[0] + 8192);
  gl_lds16(sAc2, stA[0] + 16384);
  gl_lds16(sAc3, stA[0] + 24576);
  G2S_STB(0, stB[0])
  G2S_STB(1, stB[1])
  gl_lds16(sAc0 + 64, stA[1]);
  gl_lds16(sAc1 + 64, stA[1] + 8192);
  ASM_VMCNT(4);
  __builtin_amdgcn_s_barrier();

  for (int kt0 = 0; kt0 < NT; kt0 += 2) {
#pragma unroll
    for (int par = 0; par < 2; ++par) {
      const int kt = kt0 + par;
      const int cur = par, oth = par ^ 1;
      const bool st1 = (kt + 1) < NT, st2 = (kt + 2) < NT;
      const size_t ko1 = (size_t)(kt + 1) << 6, ko2 = (size_t)(kt + 2) << 6;
      const char* Ac0 = Ak0[cur]; const char* Ac1 = Ak1[cur];
      const char* Bc0 = Bk0[cur]; const char* Bc1 = Bk1[cur];

      bf16x8 af[4][2], bfr[2][2];

#pragma unroll
      for (int mf = 0; mf < 4; ++mf) {
        af[mf][0] = *(const bf16x8*)(Ac0 + mf * 2048);
        af[mf][1] = *(const bf16x8*)(Ac1 + mf * 2048);
      }
      bfr[0][0] = *(const bf16x8*)(Bc0);
      bfr[0][1] = *(const bf16x8*)(Bc1);
      if (st1) {
        gl_lds16(sAc2 + ko1, stA[oth] + 16384);
        gl_lds16(sAc3 + ko1, stA[oth] + 24576);
      }
      __builtin_amdgcn_s_barrier();
      asm volatile("s_waitcnt lgkmcnt(0)" ::: "memory");
      __builtin_amdgcn_sched_barrier(0);
      __builtin_amdgcn_s_setprio(1);
#pragma unroll
      for (int mf = 0; mf < 4; ++mf) {
        acc[mf][0] = MFMA16(af[mf][0], bfr[0][0], acc[mf][0]);
        acc[mf][0] = MFMA16(af[mf][1], bfr[0][1], acc[mf][0]);
      }
      __builtin_amdgcn_s_setprio(0);
      __builtin_amdgcn_s_barrier();

      bfr[1][0] = *(const bf16x8*)(Bc0 + 2048);
      bfr[1][1] = *(const bf16x8*)(Bc1 + 2048);
      __builtin_amdgcn_s_barrier();
      asm volatile("s_waitcnt lgkmcnt(0)" ::: "memory");
      __builtin_amdgcn_sched_barrier(0);
      __builtin_amdgcn_s_setprio(1);
#pragma unroll
      for (int mf = 0; mf < 4; ++mf) {
        acc[mf][1] = MFMA16(af[mf][0], bfr[1][0], acc[mf][1]);
        acc[mf][1] = MFMA16(af[mf][1], bfr[1][1], acc[mf][1]);
      }
      __builtin_amdgcn_s_setprio(0);
      __builtin_amdgcn_s_barrier();

#pragma unroll
      for (int mf = 0; mf < 4; ++mf) {
        af[mf][0] = *(const bf16x8*)(Ac0 + 8192 + mf * 2048);
        af[mf][1] = *(const bf16x8*)(Ac1 + 8192 + mf * 2048);
      }
      if (st2) G2S_STB(kt + 2, stB[cur])
      __builtin_amdgcn_s_barrier();
      asm volatile("s_waitcnt lgkmcnt(0)" ::: "memory");
      __builtin_amdgcn_sched_barrier(0);
      __builtin_amdgcn_s_setprio(1);
#pragma unroll
      for (int mf = 0; mf < 4; ++mf) {
        acc[4 + mf][0] = MFMA16(af[mf][0], bfr[0][0], acc[4 + mf][0]);
        acc[4 + mf][0] = MFMA16(af[mf][1], bfr[0][1], acc[4 + mf][0]);
      }
      __builtin_amdgcn_s_setprio(0);
      __builtin_amdgcn_s_barrier();

      if (st2) {
        gl_lds16(sAc0 + ko2, stA[cur]);
        gl_lds16(sAc1 + ko2, stA[cur] + 8192);
      }
      __builtin_amdgcn_s_setprio(1);
#pragma unroll
      for (int mf = 0; mf < 4; ++mf) {
        acc[4 + mf][1] = MFMA16(af[mf][0], bfr[1][0], acc[4 + mf][1]);
        acc[4 + mf][1] = MFMA16(af[mf][1], bfr[1][1], acc[4 + mf][1]);
      }
      __builtin_amdgcn_s_setprio(0);
      if (st2) {
        ASM_VMCNT(4);
        __builtin_amdgcn_s_barrier();
      } else if (st1) {
        ASM_VMCNT(0);
        __builtin_amdgcn_s_barrier();
      }
    }
  }

  const int colb2 = bn * 128 + wn * 32;
  const int rowb = bm * 256 + wm * 128 + lg * 4;
  float bv0[2], bv1[2];
#pragma unroll
  for (int nf = 0; nf < 2; ++nf) {
    bv0[nf] = b2[colb2 + nf * 16 + lr];
    bv1[nf] = b2[1024 + colb2 + nf * 16 + lr];
  }
#pragma unroll
  for (int mf = 0; mf < 8; ++mf) {
    float g4[4], g5[4];
#pragma unroll
    for (int r = 0; r < 4; ++r) {
      const size_t row = rowb + mf * 16 + r;
      g4[r] = gate[row * 8 + 4];
      g5[r] = gate[row * 8 + 5];
    }
#pragma unroll
    for (int nf = 0; nf < 2; ++nf) {
      const int col = colb2 + nf * 16 + lr;
#pragma unroll
      for (int r = 0; r < 4; ++r) {
        out[(size_t)(rowb + mf * 16 + r) * N + col] =
            acc[mf][nf][r] + g4[r] * bv0[nf] + g5[r] * bv1[nf];
      }
    }
  }
}

// ---------------- g2sp: spec GEMM2 (h gate-folded) --------------------------
// PMODE 1: batched all experts, P[packed] = acc + gv*b2 (bf16, '=')
// PMODE 0: single expert e, out[tok] += acc + gv*b2 (fallback, sequential)
template <int PMODE>
__global__ __launch_bounds__(512, 2) void g2sp(
    const bf16* __restrict__ h_all, const bf16* __restrict__ w2t,
    const float* __restrict__ spec_b2, float* __restrict__ out,
    bf16* __restrict__ P, const float* __restrict__ gate,
    const int* __restrict__ meta, const int* __restrict__ lists, int e) {
  __shared__ __align__(1024) bf16 Alds[2 * 256 * 64];
  __shared__ __align__(1024) bf16 Blds[2 * 128 * 64];

  const int tid = threadIdx.x;
  const int lane = tid & 63, wid = tid >> 6;
  const int wm = wid >> 2, wn = wid & 3;
  const int lr = lane & 15, lg = lane >> 4;

  int bm, bn, s = e;
  if constexpr (PMODE == 1) {
    const int b = blockIdx.x;
    if (b >= meta[50]) return;
    s = (b >= meta[47]) + (b >= meta[48]) + (b >= meta[49]);
    const int local = b - meta[46 + s];
    const int nbm = (meta[24 + s] + 255) >> 8;
    const int CHm = (nbm + 3) >> 2;
    if (local >= 32 * CHm) return;
    const int xc = local & 7, idx = local >> 3;
    bm = (xc >> 1) * CHm + idx / 4;
    bn = (xc & 1) * 4 + idx % 4;
    if (bm >= nbm) return;
  } else {
    const int nbm = (meta[24 + e] + 255) >> 8;
    const int CHm = (nbm + 3) >> 2;
    if (blockIdx.x >= 8 * CHm * 4) return;
    const int xc = blockIdx.x & 7, idx = blockIdx.x >> 3;
    bm = (xc >> 1) * CHm + idx / 4;
    bn = (xc & 1) * 4 + idx % 4;
    if (bm >= nbm) return;
  }
  const int hb = meta[34 + s];
  const bf16* B = w2t + (size_t)s * DDIM * HDIM;
  const float* bias = spec_b2 + (size_t)s * DDIM;
  const int K = HDIM, N = DDIM;
  const int NT = K >> 6;

  const int L = tid * 16;
  const int rl = L >> 7;
  const int colb = (L & 127) ^ ((rl & 7) << 4);

  const int ar0 = hb + bm * 256 + rl;
  const bf16* sAc0 = h_all + (size_t)ar0 * K + (colb >> 1);
  const bf16* sAc1 = h_all + (size_t)(ar0 + 64) * K + (colb >> 1);
  const bf16* sAc2 = h_all + (size_t)(ar0 + 128) * K + (colb >> 1);
  const bf16* sAc3 = h_all + (size_t)(ar0 + 192) * K + (colb >> 1);
  const bf16* sB = B + (size_t)(bn * 128 + rl) * K + (colb >> 1);

  char* const ldsA = (char*)Alds;
  char* const ldsB = (char*)Blds;
  const int wb = wid * 1024;
  char* const stA[2] = {ldsA + wb, ldsA + 32768 + wb};
  char* const stB[2] = {ldsB + wb, ldsB + 16384 + wb};

  const int ax0 = (lg * 16) ^ ((lr & 7) << 4);
  const int ax1 = ax0 ^ 64;
  const int aro = (wm * 128 + lr) * 128;
  const int bro = (wn * 32 + lr) * 128;
  const char* const Ak0[2] = {ldsA + aro + ax0, ldsA + 32768 + aro + ax0};
  const char* const Ak1[2] = {ldsA + aro + ax1, ldsA + 32768 + aro + ax1};
  const char* const Bk0[2] = {ldsB + bro + ax0, ldsB + 16384 + bro + ax0};
  const char* const Bk1[2] = {ldsB + bro + ax1, ldsB + 16384 + bro + ax1};

  f32x4 acc[8][2] = {};

  gl_lds16(sAc0, stA[0]);
  gl_lds16(sAc1, stA[0] + 8192);
  gl_lds16(sAc2, stA[0] + 16384);
  gl_lds16(sAc3, stA[0] + 24576);
  gl_lds16(sB, stB[0]);
  gl_lds16(sB + (size_t)64 * K, stB[0] + 8192);
  gl_lds16(sB + 64, stB[1]);
  gl_lds16(sB + (size_t)64 * K + 64, stB[1] + 8192);
  gl_lds16(sAc0 + 64, stA[1]);
  gl_lds16(sAc1 + 64, stA[1] + 8192);
  ASM_VMCNT(4);
  __builtin_amdgcn_s_barrier();

  for (int kt0 = 0; kt0 < NT; kt0 += 2) {
#pragma unroll
    for (int par = 0; par < 2; ++par) {
      const int kt = kt0 + par;
      const int cur = par, oth = par ^ 1;
      const bool st1 = (kt + 1) < NT, st2 = (kt + 2) < NT;
      const size_t ko1 = (size_t)(kt + 1) << 6, ko2 = (size_t)(kt + 2) << 6;
      const char* Ac0 = Ak0[cur]; const char* Ac1 = Ak1[cur];
      const char* Bc0 = Bk0[cur]; const char* Bc1 = Bk1[cur];

      bf16x8 af[4][2], bfr[2][2];

#pragma unroll
      for (int mf = 0; mf < 4; ++mf) {
        af[mf][0] = *(const bf16x8*)(Ac0 + mf * 2048);
        af[mf][1] = *(const bf16x8*)(Ac1 + mf * 2048);
      }
      bfr[0][0] = *(const bf16x8*)(Bc0);
      bfr[0][1] = *(const bf16x8*)(Bc1);
      if (st1) {
        gl_lds16(sAc2 + ko1, stA[oth] + 16384);
        gl_lds16(sAc3 + ko1, stA[oth] + 24576);
      }
      __builtin_amdgcn_s_barrier();
      asm volatile("s_waitcnt lgkmcnt(0)" ::: "memory");
      __builtin_amdgcn_sched_barrier(0);
      __builtin_amdgcn_s_setprio(1);
#pragma unroll
      for (int mf = 0; mf < 4; ++mf) {
        acc[mf][0] = MFMA16(af[mf][0], bfr[0][0], acc[mf][0]);
        acc[mf][0] = MFMA16(af[mf][1], bfr[0][1], acc[mf][0]);
      }
      __builtin_amdgcn_s_setprio(0);
      __builtin_amdgcn_s_barrier();

      bfr[1][0] = *(const bf16x8*)(Bc0 + 2048);
      bfr[1][1] = *(const bf16x8*)(Bc1 + 2048);
      __builtin_amdgcn_s_barrier();
      asm volatile("s_waitcnt lgkmcnt(0)" ::: "memory");
      __builtin_amdgcn_sched_barrier(0);
      __builtin_amdgcn_s_setprio(1);
#pragma unroll
      for (int mf = 0; mf < 4; ++mf) {
        acc[mf][1] = MFMA16(af[mf][0], bfr[1][0], acc[mf][1]);
        acc[mf][1] = MFMA16(af[mf][1], bfr[1][1], acc[mf][1]);
      }
      __builtin_amdgcn_s_setprio(0);
      __builtin_amdgcn_s_barrier();

#pragma unroll
      for (int mf = 0; mf < 4; ++mf) {
        af[mf][0] = *(const bf16x8*)(Ac0 + 8192 + mf * 2048);
        af[mf][1] = *(const bf16x8*)(Ac1 + 8192 + mf * 2048);
      }
      if (st2) {
        gl_lds16(sB + ko2, stB[cur]);
        gl_lds16(sB + (size_t)64 * K + ko2, stB[cur] + 8192);
      }
      __builtin_amdgcn_s_barrier();
      asm volatile("s_waitcnt lgkmcnt(0)" ::: "memory");
      __builtin_amdgcn_sched_barrier(0);
      __builtin_amdgcn_s_setprio(1);
#pragma unroll
      for (int mf = 0; mf < 4; ++mf) {
        acc[4 + mf][0] = MFMA16(af[mf][0], bfr[0][0], acc[4 + mf][0]);
        acc[4 + mf][0] = MFMA16(af[mf][1], bfr[0][1], acc[4 + mf][0]);
      }
      __builtin_amdgcn_s_setprio(0);
      __builtin_amdgcn_s_barrier();

      if (st2) {
        gl_lds16(sAc0 + ko2, stA[cur]);
        gl_lds16(sAc1 + ko2, stA[cur] + 8192);
      }
      __builtin_amdgcn_s_setprio(1);
#pragma unroll
      for (int mf = 0; mf < 4; ++mf) {
        acc[4 + mf][1] = MFMA16(af[mf][0], bfr[1][0], acc[4 + mf][1]);
        acc[4 + mf][1] = MFMA16(af[mf][1], bfr[1][1], acc[4 + mf][1]);
      }
      __builtin_amdgcn_s_setprio(0);
      if (st2) {
        ASM_VMCNT(4);
        __builtin_amdgcn_s_barrier();
      } else if (st1) {
        ASM_VMCNT(0);
        __builtin_amdgcn_s_barrier();
      }
    }
  }

  const int colb2 = bn * 128 + wn * 32;
  const int rowb = bm * 256 + wm * 128 + lg * 4;
  float bv[2];
#pragma unroll
  for (int nf = 0; nf < 2; ++nf) bv[nf] = bias[colb2 + nf * 16 + lr];
  const int* lp = lists + s * 8192;
#pragma unroll
  for (int mf = 0; mf < 8; ++mf) {
    int tok[4]; float gv[4];
#pragma unroll
    for (int r = 0; r < 4; ++r) {
      tok[r] = lp[rowb + mf * 16 + r];
      gv[r] = tok[r] >= 0 ? gate[(size_t)tok[r] * 8 + s] : 0.0f;
    }
#pragma unroll
    for (int nf = 0; nf < 2; ++nf) {
      const int col = colb2 + nf * 16 + lr;
#pragma unroll
      for (int r = 0; r < 4; ++r) {
        const float v = acc[mf][nf][r] + gv[r] * bv[nf];
        if constexpr (PMODE == 1) {
          P[(size_t)(hb + rowb + mf * 16 + r) * N + col] = (bf16)v;
        } else {
          if (tok[r] >= 0) out[(size_t)tok[r] * N + col] += v;
        }
      }
    }
  }
}

// ---------------- reduce: out[t] += P[posA(t)] + P[posB(t)] -----------------
__global__ __launch_bounds__(256) void reduce_spec(
    const bf16* __restrict__ P, const int2* __restrict__ tpos,
    const int* __restrict__ meta, float* __restrict__ out) {
  const int t = blockIdx.x;
  const int c = threadIdx.x * 4;
  const int2 tp = tpos[t];
  const int ea = tp.x >> 13, pa = tp.x & 8191;
  const int eb = tp.y >> 13, pb = tp.y & 8191;
  const size_t ra = (size_t)(meta[34 + ea] + pa) * DDIM + c;
  const size_t rb = (size_t)(meta[34 + eb] + pb) * DDIM + c;
  const bf16x8* pav = (const bf16x8*)&P[ra];  // only first 4 used
  float4 o = *(float4*)&out[(size_t)t * DDIM + c];
  const bf16* A4 = &P[ra];
  const bf16* B4 = &P[rb];
  o.x += (float)A4[0] + (float)B4[0];
  o.y += (float)A4[1] + (float)B4[1];
  o.z += (float)A4[2] + (float)B4[2];
  o.w += (float)A4[3] + (float)B4[3];
  (void)pav;
  *(float4*)&out[(size_t)t * DDIM + c] = o;
}

extern "C" void kernel_launch(void* const* d_in, const int* in_sizes, int n_in,
                              void* d_out, int out_size, void* d_ws,
                              size_t ws_size, hipStream_t stream) {
  const float* x = (const float*)d_in[0];
  const float* spec_w1 = (const float*)d_in[1];
  const float* spec_b1 = (const float*)d_in[2];
  const float* spec_w2 = (const float*)d_in[3];
  const float* spec_b2 = (const float*)d_in[4];
  const float* spec_rw = (const float*)d_in[5];
  const float* spec_rb = (const float*)d_in[6];
  const float* shr_w1 = (const float*)d_in[7];
  const float* shr_b1 = (const float*)d_in[8];
  const float* shr_w2 = (const float*)d_in[9];
  const float* shr_b2 = (const float*)d_in[10];
  const float* shr_rw = (const float*)d_in[11];
  const float* shr_rb = (const float*)d_in[12];
  float* out = (float*)d_out;

  char* ws = (char*)d_ws;
  const size_t DH = (size_t)DDIM * HDIM;
  const size_t OFF_W1 = 16777216;            // xb 16 MB
  const size_t OFF_W2 = OFF_W1 + 50331648;   // w1t 48 MB
  const size_t OFF_GATE = OFF_W2 + 50331648; // w2t 48 MB
  const size_t OFF_AUX = OFF_GATE + 262144;
  const size_t OFF_META = OFF_AUX + 256;
  const size_t OFF_LIST = OFF_META + 256;
  const size_t OFF_T2 = OFF_LIST + 131072;
  const size_t OFF_P4 = OFF_T2 + 32768;
  const size_t OFF_TPOS = OFF_P4 + 131072 + 1024;
  const size_t OFF_H = OFF_TPOS + 65536;
  const size_t H_BYTES = (size_t)17408 * HDIM * 2;  // 142.6 MB (>= shr 134.2)
  const size_t OFF_P = OFF_H + H_BYTES;
  const size_t P_BYTES = (size_t)17408 * DDIM * 2;  // 35.7 MB
  bf16* xb = (bf16*)ws;
  bf16* w1t = (bf16*)(ws + OFF_W1);
  bf16* w2t = (bf16*)(ws + OFF_W2);
  float* gate = (float*)(ws + OFF_GATE);
  float* auxg = (float*)(ws + OFF_AUX);
  int* meta = (int*)(ws + OFF_META);
  int* lists = (int*)(ws + OFF_LIST);
  int* top2 = (int*)(ws + OFF_T2);
  float4* probs4 = (float4*)(ws + OFF_P4);
  int2* tpos = (int2*)(ws + OFF_TPOS);
  bf16* h = (bf16*)(ws + OFF_H);
  bf16* P = (bf16*)(ws + OFF_P);

  const bool ppath = ws_size >= OFF_P + P_BYTES;  // ~297 MB

  hipMemsetAsync(lists, 0xFF, 4 * 8192 * 4, stream);

  conv_router<<<T_TOK / 4, 256, 0, stream>>>(x, xb, spec_rw, spec_rb, shr_rw,
                                             shr_rb, gate, probs4, top2);
  scan_build<<<1, 1024, 0, stream>>>(top2, probs4, meta, lists, tpos, auxg);

  transpose_convert6<<<dim3(HDIM / 32, DDIM / 32, 6), 256, 0, stream>>>(
      spec_w1, shr_w1, w1t, DDIM, HDIM);
  transpose_convert6<<<dim3(DDIM / 32, HDIM / 32, 6), 256, 0, stream>>>(
      spec_w2, shr_w2, w2t, HDIM, DDIM);

  // 1) merged shared g1: h_shr [8192,8192] gate-folded
  g8<0><<<1024, 512, 0, stream>>>(xb, w1t + 4 * DH, shr_b1, h, 8192,
                                  8, 16, meta, lists, gate);
  // 2) merged shared g2: one K=8192 GEMM, '=' into out
  g2sh<<<256, 512, 0, stream>>>(h, w2t + 4 * DH, w2t + 5 * DH, shr_b2, out,
                                gate);
  // 3) batched spec g1 (gate-folded, packed h reuses region)
  g8<1><<<2048, 512, 0, stream>>>(xb, w1t, spec_b1, h, 4096,
                                  0, 8, meta, lists, gate);
  // 4) spec g2
  if (ppath) {
    g2sp<1><<<1024, 512, 0, stream>>>(h, w2t, spec_b2, out, P, gate, meta,
                                      lists, 0);
    reduce_spec<<<T_TOK, 256, 0, stream>>>(P, tpos, meta, out);
  } else {
    for (int e = 0; e < 4; ++e)
      g2sp<0><<<256, 512, 0, stream>>>(h, w2t, spec_b2, out, nullptr, gate,
                                       meta, lists, e);
  }
  aux_finalize<<<1, 1, 0, stream>>>(auxg, out + (size_t)T_TOK * DDIM);
}

// Round 15
// 888.622 us; speedup vs baseline: 1.1953x; 1.1953x over previous
//
#include <hip/hip_runtime.h>
#include <hip/hip_bf16.h>

#define T_TOK 8192
#define DDIM 1024
#define HDIM 4096

typedef __bf16 bf16;
typedef bf16 bf16x8 __attribute__((ext_vector_type(8)));
typedef float f32x4 __attribute__((ext_vector_type(4)));

#define ASM_VMCNT(n) asm volatile("s_waitcnt vmcnt(" #n ")" ::: "memory")
#define MFMA16(a, b, c) __builtin_amdgcn_mfma_f32_16x16x32_bf16((a), (b), (c), 0, 0, 0)
#define G8_BAR __builtin_amdgcn_s_barrier()
#define G8_WAIT                                            \
  asm volatile("s_waitcnt lgkmcnt(0)" ::: "memory");       \
  __builtin_amdgcn_sched_barrier(0)

__device__ __forceinline__ void gl_lds16(const void* g, void* l) {
  __builtin_amdgcn_global_load_lds(
      (const __attribute__((address_space(1))) unsigned int*)g,
      (__attribute__((address_space(3))) unsigned int*)l, 16, 0, 0);
}

// Fast exact-grade GELU: erf via A&S 7.1.26 (|err|<=1.5e-7 << bf16 rounding).
__device__ __forceinline__ float gelu_f(float v) {
  const float x = v * 0.7071067811865475f;
  const float ax = fabsf(x);
  const float t = 1.0f / fmaf(0.3275911f, ax, 1.0f);
  float p = fmaf(1.061405429f, t, -1.453152027f);
  p = fmaf(p, t, 1.421413741f);
  p = fmaf(p, t, -0.284496736f);
  p = fmaf(p, t, 0.254829592f);
  p = p * t;
  const float e = __expf(-ax * ax);
  const float er = fmaf(-p, e, 1.0f);
  const float erfx = (x >= 0.0f) ? er : -er;
  return 0.5f * v * (1.0f + erfx);
}

// ---------- fused: x fp32 -> bf16 convert + router probs/top2 ----------
__global__ __launch_bounds__(256) void conv_router(
    const float* __restrict__ x, bf16* __restrict__ xb,
    const float* __restrict__ srw, const float* __restrict__ srb,
    const float* __restrict__ hrw, const float* __restrict__ hrb,
    float* __restrict__ gate, float4* __restrict__ probs4,
    int* __restrict__ top2) {
  const int lane = threadIdx.x & 63;
  const int w = threadIdx.x >> 6;
  const int t = blockIdx.x * 4 + w;

  const float* xr = x + (size_t)t * DDIM;
  bf16* xbr = xb + (size_t)t * DDIM;
  float p0 = 0, p1 = 0, p2 = 0, p3 = 0, p4 = 0, p5 = 0;
#pragma unroll
  for (int c = 0; c < 4; ++c) {
    const int d = c * 256 + lane * 4;
    const float4 xv = *(const float4*)(xr + d);
    bf16 ov[4] = {(bf16)xv.x, (bf16)xv.y, (bf16)xv.z, (bf16)xv.w};
    *(float2*)(xbr + d) = *(float2*)ov;
    const float xa[4] = {xv.x, xv.y, xv.z, xv.w};
#pragma unroll
    for (int j = 0; j < 4; ++j) {
      const float xd = xa[j];
      const float4 r4 = *(const float4*)(srw + (size_t)(d + j) * 4);
      p0 += xd * r4.x; p1 += xd * r4.y; p2 += xd * r4.z; p3 += xd * r4.w;
      const float2 r2 = *(const float2*)(hrw + (size_t)(d + j) * 2);
      p4 += xd * r2.x; p5 += xd * r2.y;
    }
  }
#pragma unroll
  for (int off = 32; off >= 1; off >>= 1) {
    p0 += __shfl_xor(p0, off);
    p1 += __shfl_xor(p1, off);
    p2 += __shfl_xor(p2, off);
    p3 += __shfl_xor(p3, off);
    p4 += __shfl_xor(p4, off);
    p5 += __shfl_xor(p5, off);
  }
  if (lane == 0) {
    const float l0 = p0 + srb[0], l1 = p1 + srb[1];
    const float l2 = p2 + srb[2], l3 = p3 + srb[3];
    const float m = fmaxf(fmaxf(l0, l1), fmaxf(l2, l3));
    const float e0 = expf(l0 - m), e1 = expf(l1 - m);
    const float e2 = expf(l2 - m), e3 = expf(l3 - m);
    const float s = e0 + e1 + e2 + e3;
    float pr[4] = {e0 / s, e1 / s, e2 / s, e3 / s};
    int i1 = 0; float v1 = pr[0];
#pragma unroll
    for (int e = 1; e < 4; ++e) if (pr[e] > v1) { v1 = pr[e]; i1 = e; }
    int i2 = -1; float v2 = -1.0f;
#pragma unroll
    for (int e = 0; e < 4; ++e)
      if (e != i1 && pr[e] > v2) { v2 = pr[e]; i2 = e; }
    float g[4] = {0, 0, 0, 0};
    g[i1] = v1; g[i2] = v2;
    float* gr = gate + (size_t)t * 8;
    gr[0] = g[0]; gr[1] = g[1]; gr[2] = g[2]; gr[3] = g[3];
    const float h0 = p4 + hrb[0], h1 = p5 + hrb[1];
    const float mh = fmaxf(h0, h1);
    const float q0 = expf(h0 - mh), q1 = expf(h1 - mh);
    const float qs = q0 + q1;
    gr[4] = q0 / qs; gr[5] = q1 / qs; gr[6] = 0; gr[7] = 0;
    probs4[t] = make_float4(pr[0], pr[1], pr[2], pr[3]);
    top2[t] = i1 | (i2 << 8);
  }
}

// ---- weight transpose+convert, 6 experts per dispatch (z: 0-3 spec, 4-5 shr)
__global__ __launch_bounds__(256) void transpose_convert6(
    const float* __restrict__ spec_w, const float* __restrict__ shr_w,
    bf16* __restrict__ dst, int R, int C) {
  __shared__ float tile[32][33];
  const int z = blockIdx.z;
  const float* src = (z < 4) ? spec_w + (size_t)z * R * C
                             : shr_w + (size_t)(z - 4) * R * C;
  bf16* d = dst + (size_t)z * R * C;
  const int c0 = blockIdx.x * 32, r0 = blockIdx.y * 32;
  const int tx = threadIdx.x & 31, ty = threadIdx.x >> 5;
#pragma unroll
  for (int i = 0; i < 4; ++i)
    tile[ty + 8 * i][tx] = src[(size_t)(r0 + ty + 8 * i) * C + c0 + tx];
  __syncthreads();
#pragma unroll
  for (int i = 0; i < 4; ++i)
    d[(size_t)(c0 + ty + 8 * i) * R + r0 + tx] = (bf16)tile[tx][ty + 8 * i];
}

// ---------------- router pass 2: scan -> lists / tpos / meta / aux ----------
// meta[24..27] spec counts; meta[34..37] packed h row base per spec expert;
// meta[40..44] spec-g1 block prefix (64*ch); meta[46..50] spec-g2 prefix (32*ch)
__global__ __launch_bounds__(1024) void scan_build(
    const int* __restrict__ top2, const float4* __restrict__ probs4,
    int* __restrict__ meta, int* __restrict__ lists, int2* __restrict__ tpos,
    float* __restrict__ auxg) {
  __shared__ unsigned long long sc[1024];
  __shared__ float4 rp[512];
  const int tid = threadIdx.x;

  int ee[8];
  unsigned long long c = 0;
  float4 ps = make_float4(0.f, 0.f, 0.f, 0.f);
#pragma unroll
  for (int j = 0; j < 8; ++j) {
    const int t = tid * 8 + j;
    const int p = top2[t];
    ee[j] = p;
    const int a = p & 15, b = (p >> 8) & 15;
    c += (1ULL << (16 * a)) + (1ULL << (16 * b));
    const float4 pv = probs4[t];
    ps.x += pv.x; ps.y += pv.y; ps.z += pv.z; ps.w += pv.w;
  }
  sc[tid] = c;
  __syncthreads();
  for (int off = 1; off < 1024; off <<= 1) {
    const unsigned long long mine = sc[tid];
    const unsigned long long prev = (tid >= off) ? sc[tid - off] : 0ULL;
    __syncthreads();
    sc[tid] = mine + prev;
    __syncthreads();
  }
  const unsigned long long incl = sc[tid];
  const unsigned long long tot = sc[1023];
  const unsigned long long excl = incl - c;
  int q0 = (int)(excl & 0xffff), q1 = (int)((excl >> 16) & 0xffff);
  int q2 = (int)((excl >> 32) & 0xffff), q3 = (int)((excl >> 48) & 0xffff);
#pragma unroll
  for (int j = 0; j < 8; ++j) {
    const int t = tid * 8 + j;
    const int a = ee[j] & 15, b = (ee[j] >> 8) & 15;
    const int pa = (a == 0) ? q0 : (a == 1) ? q1 : (a == 2) ? q2 : q3;
    lists[a * 8192 + pa] = t;
    q0 += (a == 0); q1 += (a == 1); q2 += (a == 2); q3 += (a == 3);
    const int pb = (b == 0) ? q0 : (b == 1) ? q1 : (b == 2) ? q2 : q3;
    lists[b * 8192 + pb] = t;
    q0 += (b == 0); q1 += (b == 1); q2 += (b == 2); q3 += (b == 3);
    tpos[t] = make_int2(a * 8192 + pa, b * 8192 + pb);
  }
  if (tid == 1023) {
    const int c0 = (int)(tot & 0xffff), c1 = (int)((tot >> 16) & 0xffff);
    const int c2 = (int)((tot >> 32) & 0xffff), c3 = (int)((tot >> 48) & 0xffff);
    meta[24] = c0; meta[25] = c1; meta[26] = c2; meta[27] = c3;
    auxg[0] = (float)c0; auxg[1] = (float)c1;
    auxg[2] = (float)c2; auxg[3] = (float)c3;
    const int nb0 = (c0 + 255) >> 8, nb1 = (c1 + 255) >> 8;
    const int nb2 = (c2 + 255) >> 8, nb3 = (c3 + 255) >> 8;
    const int ch0 = (nb0 + 3) >> 2, ch1 = (nb1 + 3) >> 2;
    const int ch2 = (nb2 + 3) >> 2, ch3 = (nb3 + 3) >> 2;
    meta[34] = 0;
    meta[35] = nb0 * 256;
    meta[36] = meta[35] + nb1 * 256;
    meta[37] = meta[36] + nb2 * 256;
    meta[40] = 0;
    meta[41] = 64 * ch0;
    meta[42] = meta[41] + 64 * ch1;
    meta[43] = meta[42] + 64 * ch2;
    meta[44] = meta[43] + 64 * ch3;
    meta[46] = 0;
    meta[47] = 32 * ch0;
    meta[48] = meta[47] + 32 * ch1;
    meta[49] = meta[48] + 32 * ch2;
    meta[50] = meta[49] + 32 * ch3;
  }
  if (tid >= 512) rp[tid - 512] = ps;
  __syncthreads();
  if (tid < 512) {
    const float4 o = rp[tid];
    ps.x += o.x; ps.y += o.y; ps.z += o.z; ps.w += o.w;
  }
  for (int w = 256; w >= 1; w >>= 1) {
    __syncthreads();
    if (tid >= w && tid < 2 * w) rp[tid - w] = ps;
    __syncthreads();
    if (tid < w) {
      const float4 o = rp[tid];
      ps.x += o.x; ps.y += o.y; ps.z += o.z; ps.w += o.w;
    }
  }
  if (tid == 0) {
    auxg[4] = ps.x; auxg[5] = ps.y; auxg[6] = ps.z; auxg[7] = ps.w;
  }
}

__global__ void aux_finalize(const float* __restrict__ auxg,
                             float* __restrict__ outp) {
  float a = 0.0f;
#pragma unroll
  for (int e = 0; e < 4; ++e)
    a += (auxg[e] / (float)(T_TOK * 2)) * (auxg[4 + e] / (float)T_TOK);
  outp[0] = 4.0f * a;
}

// ---------------- g8: 8-phase 256x256 GEMM1  h = gelu(A*B^T + b1) ----------
// KIND 0: dense rows, merged shared N=8192. KIND 1: spec batched (segments
// via meta[40..44], packed hb = meta[34+s]).  (R13-identical, NO gate fold.)
template <int KIND>
__global__ __launch_bounds__(512, 2) void g8(
    const bf16* __restrict__ A, const bf16* __restrict__ Bw,
    const float* __restrict__ bias, bf16* __restrict__ h_all, int N,
    int CH_M, int CH_N, const int* __restrict__ meta,
    const int* __restrict__ lists) {
  __shared__ __align__(1024) bf16 Alds[2 * 256 * 64];
  __shared__ __align__(1024) bf16 Blds[2 * 256 * 64];

  const int tid = threadIdx.x;
  const int lane = tid & 63, wid = tid >> 6;
  const int wm = wid >> 2, wn = wid & 3;
  const int lr = lane & 15, lg = lane >> 4;

  int bm, bn, hb = 0, s = 0;
  const bf16* Bp = Bw;
  const float* biasp = bias;
  if constexpr (KIND == 0) {
    const int xcd = blockIdx.x & 7, idx = blockIdx.x >> 3;
    bm = (xcd >> 1) * CH_M + idx / CH_N;
    bn = (xcd & 1) * CH_N + idx % CH_N;
  } else {
    const int b = blockIdx.x;
    if (b >= meta[44]) return;
    s = (b >= meta[41]) + (b >= meta[42]) + (b >= meta[43]);
    const int local = b - meta[40 + s];
    const int nbm = (meta[24 + s] + 255) >> 8;
    const int CHm = (nbm + 3) >> 2;
    if (local >= 64 * CHm) return;
    const int xc = local & 7, idx = local >> 3;
    bm = (xc >> 1) * CHm + idx / 8;
    bn = (xc & 1) * 8 + idx % 8;
    if (bm >= nbm) return;
    hb = meta[34 + s];
    Bp = Bw + (size_t)s * DDIM * HDIM;
    biasp = bias + (size_t)s * HDIM;
  }
  const int K = DDIM;
  const int NT = K >> 6;  // 16

  const int rl = tid >> 3;
  const int cbs = ((tid * 16) & 127) ^ ((rl & 7) << 4);
  int ar[4];
#pragma unroll
  for (int c = 0; c < 4; ++c) ar[c] = bm * 256 + c * 64 + rl;
  if constexpr (KIND != 0) {
    const int* lp = lists + s * 8192;
#pragma unroll
    for (int c = 0; c < 4; ++c) {
      const int t = lp[ar[c]];
      ar[c] = t < 0 ? 0 : t;
    }
  }
  const bf16* sA[4];
  const bf16* sB[4];
#pragma unroll
  for (int c = 0; c < 4; ++c) {
    sA[c] = A + (size_t)ar[c] * K + (cbs >> 1);
    sB[c] = Bp + (size_t)(bn * 256 + c * 64 + rl) * K + (cbs >> 1);
  }
  char* const ldsA = (char*)Alds;
  char* const ldsB = (char*)Blds;
  const int wb = wid * 1024;

  const int ax0 = (lg * 16) ^ ((lr & 7) << 4);
  const int ax1 = ax0 ^ 64;
  const int aro = (wm * 128 + lr) * 128;
  const int bro = (wn * 64 + lr) * 128;
  const char* const A0 = (const char*)Alds + aro + ax0;
  const char* const A1 = (const char*)Alds + aro + ax1;
  const char* const B0 = (const char*)Blds + bro + ax0;
  const char* const B1 = (const char*)Blds + bro + ax1;

  f32x4 acc[8][4] = {};
  bf16x8 af[4][2], b01[2][2], b23[2][2];

#define G8_RA(BOFF, MB)                                               \
  _Pragma("unroll") for (int i = 0; i < 4; ++i) {                     \
    af[i][0] = *(const bf16x8*)(A0 + (BOFF) + ((MB) + i) * 2048);     \
    af[i][1] = *(const bf16x8*)(A1 + (BOFF) + ((MB) + i) * 2048);     \
  }
#define G8_RB(BOFF, DST, NB)                                          \
  _Pragma("unroll") for (int i = 0; i < 2; ++i) {                     \
    DST[i][0] = *(const bf16x8*)(B0 + (BOFF) + ((NB) + i) * 2048);    \
    DST[i][1] = *(const bf16x8*)(B1 + (BOFF) + ((NB) + i) * 2048);    \
  }
#define G8_MMA(MB, NB, BSRC)                                          \
  __builtin_amdgcn_s_setprio(1);                                      \
  _Pragma("unroll") for (int i = 0; i < 4; ++i)                       \
    _Pragma("unroll") for (int j = 0; j < 2; ++j) {                   \
      acc[(MB) + i][(NB) + j] =                                       \
          MFMA16(af[i][0], BSRC[j][0], acc[(MB) + i][(NB) + j]);      \
      acc[(MB) + i][(NB) + j] =                                       \
          MFMA16(af[i][1], BSRC[j][1], acc[(MB) + i][(NB) + j]);      \
    }                                                                 \
  __builtin_amdgcn_s_setprio(0);
#define G8_STG_B(T, C, BUFO)                                          \
  gl_lds16(sB[C] + (size_t)(T) * 64, ldsB + (BUFO) + (C) * 8192 + wb);
#define G8_STG_A(T, C, BUFO)                                          \
  gl_lds16(sA[C] + (size_t)(T) * 64, ldsA + (BUFO) + (C) * 8192 + wb);

  G8_STG_B(0, 0, 0) G8_STG_B(0, 1, 0) G8_STG_B(0, 2, 0) G8_STG_B(0, 3, 0)
  G8_STG_A(0, 0, 0) G8_STG_A(0, 1, 0) G8_STG_A(0, 2, 0) G8_STG_A(0, 3, 0)
  G8_STG_B(1, 0, 32768) G8_STG_B(1, 1, 32768)
  G8_STG_B(1, 2, 32768) G8_STG_B(1, 3, 32768)
  G8_STG_A(1, 0, 32768) G8_STG_A(1, 1, 32768)
  G8_STG_A(1, 2, 32768) G8_STG_A(1, 3, 32768)
  ASM_VMCNT(8);
  G8_BAR;

  for (int t = 0; t < NT; t += 2) {
    const bool stg = (t + 2) < NT;
    G8_RA(0, 0);
    G8_RB(0, b01, 0);
    G8_BAR; G8_WAIT;
    G8_MMA(0, 0, b01);
    G8_BAR;
    G8_RB(0, b23, 2);
    G8_BAR; G8_WAIT;
    G8_MMA(0, 2, b23);
    G8_BAR;
    G8_RA(0, 4);
    if (stg) { G8_STG_B(t + 2, 0, 0) G8_STG_B(t + 2, 1, 0) }
    G8_BAR; G8_WAIT;
    G8_MMA(4, 0, b01);
    G8_BAR;
    if (stg) { G8_STG_B(t + 2, 2, 0) G8_STG_B(t + 2, 3, 0) }
    G8_MMA(4, 2, b23);
    if (stg) ASM_VMCNT(4); else ASM_VMCNT(0);
    G8_BAR;
    G8_RA(32768, 0);
    G8_RB(32768, b01, 0);
    if (stg) { G8_STG_A(t + 2, 0, 0) G8_STG_A(t + 2, 1, 0) }
    G8_BAR; G8_WAIT;
    G8_MMA(0, 0, b01);
    G8_BAR;
    G8_RB(32768, b23, 2);
    if (stg) { G8_STG_A(t + 2, 2, 0) G8_STG_A(t + 2, 3, 0) }
    G8_BAR; G8_WAIT;
    G8_MMA(0, 2, b23);
    G8_BAR;
    G8_RA(32768, 4);
    if (stg) {
      G8_STG_B(t + 3, 0, 32768) G8_STG_B(t + 3, 1, 32768)
      G8_STG_B(t + 3, 2, 32768) G8_STG_B(t + 3, 3, 32768)
    }
    G8_BAR; G8_WAIT;
    G8_MMA(4, 0, b01);
    G8_BAR;
    if (stg) {
      G8_STG_A(t + 3, 0, 32768) G8_STG_A(t + 3, 1, 32768)
      G8_STG_A(t + 3, 2, 32768) G8_STG_A(t + 3, 3, 32768)
    }
    G8_MMA(4, 2, b23);
    if (stg) ASM_VMCNT(8);
    G8_BAR;
  }

  const int colb = bn * 256 + wn * 64;
  const int rowb = hb + bm * 256 + wm * 128 + lg * 4;
  float bv[4];
#pragma unroll
  for (int nf = 0; nf < 4; ++nf) bv[nf] = biasp[colb + nf * 16 + lr];
#pragma unroll
  for (int mf = 0; mf < 8; ++mf)
#pragma unroll
    for (int nf = 0; nf < 4; ++nf) {
      const int col = colb + nf * 16 + lr;
#pragma unroll
      for (int r = 0; r < 4; ++r) {
        const int row = rowb + mf * 16 + r;
        h_all[(size_t)row * N + col] = (bf16)gelu_f(acc[mf][nf][r] + bv[nf]);
      }
    }
}

// ---------------- g2k: shared GEMM2 out = / += gate*(h*W2^T + b2) -----------
// 4-phase dbuf inner loop, A row stride lda. EMODE 0: '='; 1: '+='.
template <int EMODE>
__global__ __launch_bounds__(512, 2) void g2k(
    const bf16* __restrict__ A, int lda, const bf16* __restrict__ B,
    const float* __restrict__ bias, float* __restrict__ out,
    const float* __restrict__ gate, int gidx) {
  __shared__ __align__(1024) bf16 Alds[2 * 256 * 64];
  __shared__ __align__(1024) bf16 Blds[2 * 128 * 64];

  const int tid = threadIdx.x;
  const int lane = tid & 63, wid = tid >> 6;
  const int wm = wid >> 2, wn = wid & 3;
  const int lr = lane & 15, lg = lane >> 4;

  const int xcd = blockIdx.x & 7, idx = blockIdx.x >> 3;
  const int bm = (xcd >> 1) * 8 + idx / 4;
  const int bn = (xcd & 1) * 4 + idx % 4;
  const int K = HDIM, N = DDIM;
  const int NT = K >> 6;

  const int L = tid * 16;
  const int rl = L >> 7;
  const int colb = (L & 127) ^ ((rl & 7) << 4);

  const int ar0 = bm * 256 + rl;
  const bf16* sAc0 = A + (size_t)ar0 * lda + (colb >> 1);
  const bf16* sAc1 = A + (size_t)(ar0 + 64) * lda + (colb >> 1);
  const bf16* sAc2 = A + (size_t)(ar0 + 128) * lda + (colb >> 1);
  const bf16* sAc3 = A + (size_t)(ar0 + 192) * lda + (colb >> 1);
  const bf16* sB = B + (size_t)(bn * 128 + rl) * K + (colb >> 1);

  char* const ldsA = (char*)Alds;
  char* const ldsB = (char*)Blds;
  const int wb = wid * 1024;
  char* const stA[2] = {ldsA + wb, ldsA + 32768 + wb};
  char* const stB[2] = {ldsB + wb, ldsB + 16384 + wb};

  const int ax0 = (lg * 16) ^ ((lr & 7) << 4);
  const int ax1 = ax0 ^ 64;
  const int aro = (wm * 128 + lr) * 128;
  const int bro = (wn * 32 + lr) * 128;
  const char* const Ak0[2] = {ldsA + aro + ax0, ldsA + 32768 + aro + ax0};
  const char* const Ak1[2] = {ldsA + aro + ax1, ldsA + 32768 + aro + ax1};
  const char* const Bk0[2] = {ldsB + bro + ax0, ldsB + 16384 + bro + ax0};
  const char* const Bk1[2] = {ldsB + bro + ax1, ldsB + 16384 + bro + ax1};

  f32x4 acc[8][2] = {};

  gl_lds16(sAc0, stA[0]);
  gl_lds16(sAc1, stA[0] + 8192);
  gl_lds16(sAc2, stA[0] + 16384);
  gl_lds16(sAc3, stA[0] + 24576);
  gl_lds16(sB, stB[0]);
  gl_lds16(sB + (size_t)64 * K, stB[0] + 8192);
  gl_lds16(sB + 64, stB[1]);
  gl_lds16(sB + (size_t)64 * K + 64, stB[1] + 8192);
  gl_lds16(sAc0 + 64, stA[1]);
  gl_lds16(sAc1 + 64, stA[1] + 8192);
  ASM_VMCNT(4);
  __builtin_amdgcn_s_barrier();

  for (int kt0 = 0; kt0 < NT; kt0 += 2) {
#pragma unroll
    for (int par = 0; par < 2; ++par) {
      const int kt = kt0 + par;
      const int cur = par, oth = par ^ 1;
      const bool st1 = (kt + 1) < NT, st2 = (kt + 2) < NT;
      const size_t ko1 = (size_t)(kt + 1) << 6, ko2 = (size_t)(kt + 2) << 6;
      const char* Ac0 = Ak0[cur]; const char* Ac1 = Ak1[cur];
      const char* Bc0 = Bk0[cur]; const char* Bc1 = Bk1[cur];

      bf16x8 af[4][2], bfr[2][2];

#pragma unroll
      for (int mf = 0; mf < 4; ++mf) {
        af[mf][0] = *(const bf16x8*)(Ac0 + mf * 2048);
        af[mf][1] = *(const bf16x8*)(Ac1 + mf * 2048);
      }
      bfr[0][0] = *(const bf16x8*)(Bc0);
      bfr[0][1] = *(const bf16x8*)(Bc1);
      if (st1) {
        gl_lds16(sAc2 + ko1, stA[oth] + 16384);
        gl_lds16(sAc3 + ko1, stA[oth] + 24576);
      }
      __builtin_amdgcn_s_barrier();
      asm volatile("s_waitcnt lgkmcnt(0)" ::: "memory");
      __builtin_amdgcn_sched_barrier(0);
      __builtin_amdgcn_s_setprio(1);
#pragma unroll
      for (int mf = 0; mf < 4; ++mf) {
        acc[mf][0] = MFMA16(af[mf][0], bfr[0][0], acc[mf][0]);
        acc[mf][0] = MFMA16(af[mf][1], bfr[0][1], acc[mf][0]);
      }
      __builtin_amdgcn_s_setprio(0);
      __builtin_amdgcn_s_barrier();

      bfr[1][0] = *(const bf16x8*)(Bc0 + 2048);
      bfr[1][1] = *(const bf16x8*)(Bc1 + 2048);
      __builtin_amdgcn_s_barrier();
      asm volatile("s_waitcnt lgkmcnt(0)" ::: "memory");
      __builtin_amdgcn_sched_barrier(0);
      __builtin_amdgcn_s_setprio(1);
#pragma unroll
      for (int mf = 0; mf < 4; ++mf) {
        acc[mf][1] = MFMA16(af[mf][0], bfr[1][0], acc[mf][1]);
        acc[mf][1] = MFMA16(af[mf][1], bfr[1][1], acc[mf][1]);
      }
      __builtin_amdgcn_s_setprio(0);
      __builtin_amdgcn_s_barrier();

#pragma unroll
      for (int mf = 0; mf < 4; ++mf) {
        af[mf][0] = *(const bf16x8*)(Ac0 + 8192 + mf * 2048);
        af[mf][1] = *(const bf16x8*)(Ac1 + 8192 + mf * 2048);
      }
      if (st2) {
        gl_lds16(sB + ko2, stB[cur]);
        gl_lds16(sB + (size_t)64 * K + ko2, stB[cur] + 8192);
      }
      __builtin_amdgcn_s_barrier();
      asm volatile("s_waitcnt lgkmcnt(0)" ::: "memory");
      __builtin_amdgcn_sched_barrier(0);
      __builtin_amdgcn_s_setprio(1);
#pragma unroll
      for (int mf = 0; mf < 4; ++mf) {
        acc[4 + mf][0] = MFMA16(af[mf][0], bfr[0][0], acc[4 + mf][0]);
        acc[4 + mf][0] = MFMA16(af[mf][1], bfr[0][1], acc[4 + mf][0]);
      }
      __builtin_amdgcn_s_setprio(0);
      __builtin_amdgcn_s_barrier();

      if (st2) {
        gl_lds16(sAc0 + ko2, stA[cur]);
        gl_lds16(sAc1 + ko2, stA[cur] + 8192);
      }
      __builtin_amdgcn_s_setprio(1);
#pragma unroll
      for (int mf = 0; mf < 4; ++mf) {
        acc[4 + mf][1] = MFMA16(af[mf][0], bfr[1][0], acc[4 + mf][1]);
        acc[4 + mf][1] = MFMA16(af[mf][1], bfr[1][1], acc[4 + mf][1]);
      }
      __builtin_amdgcn_s_setprio(0);
      if (st2) {
        ASM_VMCNT(4);
        __builtin_amdgcn_s_barrier();
      } else if (st1) {
        ASM_VMCNT(0);
        __builtin_amdgcn_s_barrier();
      }
    }
  }

  const int colb2 = bn * 128 + wn * 32;
  const int rowb = bm * 256 + wm * 128 + lg * 4;
  float bv[2];
#pragma unroll
  for (int nf = 0; nf < 2; ++nf) bv[nf] = bias[colb2 + nf * 16 + lr];
#pragma unroll
  for (int mf = 0; mf < 8; ++mf) {
    float gv[4];
#pragma unroll
    for (int r = 0; r < 4; ++r)
      gv[r] = gate[(size_t)(rowb + mf * 16 + r) * 8 + gidx];
#pragma unroll
    for (int nf = 0; nf < 2; ++nf) {
      const int col = colb2 + nf * 16 + lr;
#pragma unroll
      for (int r = 0; r < 4; ++r) {
        const float v = acc[mf][nf][r] + bv[nf];
        const size_t oi = (size_t)(rowb + mf * 16 + r) * N + col;
        if constexpr (EMODE == 1)
          out[oi] += gv[r] * v;
        else
          out[oi] = gv[r] * v;
      }
    }
  }
}

// ---------------- g2sp: spec GEMM2 batched -> P (gated partials, '=') -------
__global__ __launch_bounds__(512, 2) void g2sp(
    const bf16* __restrict__ h_all, const bf16* __restrict__ w2t,
    const float* __restrict__ spec_b2, bf16* __restrict__ P,
    const float* __restrict__ gate, const int* __restrict__ meta,
    const int* __restrict__ lists) {
  __shared__ __align__(1024) bf16 Alds[2 * 256 * 64];
  __shared__ __align__(1024) bf16 Blds[2 * 128 * 64];

  const int tid = threadIdx.x;
  const int lane = tid & 63, wid = tid >> 6;
  const int wm = wid >> 2, wn = wid & 3;
  const int lr = lane & 15, lg = lane >> 4;

  const int b = blockIdx.x;
  if (b >= meta[50]) return;
  const int s = (b >= meta[47]) + (b >= meta[48]) + (b >= meta[49]);
  const int local = b - meta[46 + s];
  const int nbm = (meta[24 + s] + 255) >> 8;
  const int CHm = (nbm + 3) >> 2;
  if (local >= 32 * CHm) return;
  const int xc = local & 7, idx = local >> 3;
  int bm = (xc >> 1) * CHm + idx / 4;
  int bn = (xc & 1) * 4 + idx % 4;
  if (bm >= nbm) return;

  const int hb = meta[34 + s];
  const bf16* B = w2t + (size_t)s * DDIM * HDIM;
  const float* bias = spec_b2 + (size_t)s * DDIM;
  const int K = HDIM, N = DDIM;
  const int NT = K >> 6;

  const int L = tid * 16;
  const int rl = L >> 7;
  const int colb = (L & 127) ^ ((rl & 7) << 4);

  const int ar0 = hb + bm * 256 + rl;
  const bf16* sAc0 = h_all + (size_t)ar0 * K + (colb >> 1);
  const bf16* sAc1 = h_all + (size_t)(ar0 + 64) * K + (colb >> 1);
  const bf16* sAc2 = h_all + (size_t)(ar0 + 128) * K + (colb >> 1);
  const bf16* sAc3 = h_all + (size_t)(ar0 + 192) * K + (colb >> 1);
  const bf16* sB = B + (size_t)(bn * 128 + rl) * K + (colb >> 1);

  char* const ldsA = (char*)Alds;
  char* const ldsB = (char*)Blds;
  const int wb = wid * 1024;
  char* const stA[2] = {ldsA + wb, ldsA + 32768 + wb};
  char* const stB[2] = {ldsB + wb, ldsB + 16384 + wb};

  const int ax0 = (lg * 16) ^ ((lr & 7) << 4);
  const int ax1 = ax0 ^ 64;
  const int aro = (wm * 128 + lr) * 128;
  const int bro = (wn * 32 + lr) * 128;
  const char* const Ak0[2] = {ldsA + aro + ax0, ldsA + 32768 + aro + ax0};
  const char* const Ak1[2] = {ldsA + aro + ax1, ldsA + 32768 + aro + ax1};
  const char* const Bk0[2] = {ldsB + bro + ax0, ldsB + 16384 + bro + ax0};
  const char* const Bk1[2] = {ldsB + bro + ax1, ldsB + 16384 + bro + ax1};

  f32x4 acc[8][2] = {};

  gl_lds16(sAc0, stA[0]);
  gl_lds16(sAc1, stA[0] + 8192);
  gl_lds16(sAc2, stA[0] + 16384);
  gl_lds16(sAc3, stA[0] + 24576);
  gl_lds16(sB, stB[0]);
  gl_lds16(sB + (size_t)64 * K, stB[0] + 8192);
  gl_lds16(sB + 64, stB[1]);
  gl_lds16(sB + (size_t)64 * K + 64, stB[1] + 8192);
  gl_lds16(sAc0 + 64, stA[1]);
  gl_lds16(sAc1 + 64, stA[1] + 8192);
  ASM_VMCNT(4);
  __builtin_amdgcn_s_barrier();

  for (int kt0 = 0; kt0 < NT; kt0 += 2) {
#pragma unroll
    for (int par = 0; par < 2; ++par) {
      const int kt = kt0 + par;
      const int cur = par, oth = par ^ 1;
      const bool st1 = (kt + 1) < NT, st2 = (kt + 2) < NT;
      const size_t ko1 = (size_t)(kt + 1) << 6, ko2 = (size_t)(kt + 2) << 6;
      const char* Ac0 = Ak0[cur]; const char* Ac1 = Ak1[cur];
      const char* Bc0 = Bk0[cur]; const char* Bc1 = Bk1[cur];

      bf16x8 af[4][2], bfr[2][2];

#pragma unroll
      for (int mf = 0; mf < 4; ++mf) {
        af[mf][0] = *(const bf16x8*)(Ac0 + mf * 2048);
        af[mf][1] = *(const bf16x8*)(Ac1 + mf * 2048);
      }
      bfr[0][0] = *(const bf16x8*)(Bc0);
      bfr[0][1] = *(const bf16x8*)(Bc1);
      if (st1) {
        gl_lds16(sAc2 + ko1, stA[oth] + 16384);
        gl_lds16(sAc3 + ko1, stA[oth] + 24576);
      }
      __builtin_amdgcn_s_barrier();
      asm volatile("s_waitcnt lgkmcnt(0)" ::: "memory");
      __builtin_amdgcn_sched_barrier(0);
      __builtin_amdgcn_s_setprio(1);
#pragma unroll
      for (int mf = 0; mf < 4; ++mf) {
        acc[mf][0] = MFMA16(af[mf][0], bfr[0][0], acc[mf][0]);
        acc[mf][0] = MFMA16(af[mf][1], bfr[0][1], acc[mf][0]);
      }
      __builtin_amdgcn_s_setprio(0);
      __builtin_amdgcn_s_barrier();

      bfr[1][0] = *(const bf16x8*)(Bc0 + 2048);
      bfr[1][1] = *(const bf16x8*)(Bc1 + 2048);
      __builtin_amdgcn_s_barrier();
      asm volatile("s_waitcnt lgkmcnt(0)" ::: "memory");
      __builtin_amdgcn_sched_barrier(0);
      __builtin_amdgcn_s_setprio(1);
#pragma unroll
      for (int mf = 0; mf < 4; ++mf) {
        acc[mf][1] = MFMA16(af[mf][0], bfr[1][0], acc[mf][1]);
        acc[mf][1] = MFMA16(af[mf][1], bfr[1][1], acc[mf][1]);
      }
      __builtin_amdgcn_s_setprio(0);
      __builtin_amdgcn_s_barrier();

#pragma unroll
      for (int mf = 0; mf < 4; ++mf) {
        af[mf][0] = *(const bf16x8*)(Ac0 + 8192 + mf * 2048);
        af[mf][1] = *(const bf16x8*)(Ac1 + 8192 + mf * 2048);
      }
      if (st2) {
        gl_lds16(sB + ko2, stB[cur]);
        gl_lds16(sB + (size_t)64 * K + ko2, stB[cur] + 8192);
      }
      __builtin_amdgcn_s_barrier();
      asm volatile("s_waitcnt lgkmcnt(0)" ::: "memory");
      __builtin_amdgcn_sched_barrier(0);
      __builtin_amdgcn_s_setprio(1);
#pragma unroll
      for (int mf = 0; mf < 4; ++mf) {
        acc[4 + mf][0] = MFMA16(af[mf][0], bfr[0][0], acc[4 + mf][0]);
        acc[4 + mf][0] = MFMA16(af[mf][1], bfr[0][1], acc[4 + mf][0]);
      }
      __builtin_amdgcn_s_setprio(0);
      __builtin_amdgcn_s_barrier();

      if (st2) {
        gl_lds16(sAc0 + ko2, stA[cur]);
        gl_lds16(sAc1 + ko2, stA[cur] + 8192);
      }
      __builtin_amdgcn_s_setprio(1);
#pragma unroll
      for (int mf = 0; mf < 4; ++mf) {
        acc[4 + mf][1] = MFMA16(af[mf][0], bfr[1][0], acc[4 + mf][1]);
        acc[4 + mf][1] = MFMA16(af[mf][1], bfr[1][1], acc[4 + mf][1]);
      }
      __builtin_amdgcn_s_setprio(0);
      if (st2) {
        ASM_VMCNT(4);
        __builtin_amdgcn_s_barrier();
      } else if (st1) {
        ASM_VMCNT(0);
        __builtin_amdgcn_s_barrier();
      }
    }
  }

  const int colb2 = bn * 128 + wn * 32;
  const int rowb = bm * 256 + wm * 128 + lg * 4;
  float bv[2];
#pragma unroll
  for (int nf = 0; nf < 2; ++nf) bv[nf] = bias[colb2 + nf * 16 + lr];
  const int* lp = lists + s * 8192;
#pragma unroll
  for (int mf = 0; mf < 8; ++mf) {
    int tok[4]; float gv[4];
#pragma unroll
    for (int r = 0; r < 4; ++r) {
      tok[r] = lp[rowb + mf * 16 + r];
      gv[r] = tok[r] >= 0 ? gate[(size_t)tok[r] * 8 + s] : 0.0f;
    }
#pragma unroll
    for (int nf = 0; nf < 2; ++nf) {
      const int col = colb2 + nf * 16 + lr;
#pragma unroll
      for (int r = 0; r < 4; ++r) {
        const float v = gv[r] * (acc[mf][nf][r] + bv[nf]);
        P[(size_t)(hb + rowb + mf * 16 + r) * N + col] = (bf16)v;
      }
    }
  }
}

// ---------------- reduce: out[t] += P[posA(t)] + P[posB(t)] -----------------
__global__ __launch_bounds__(256) void reduce_spec(
    const bf16* __restrict__ P, const int2* __restrict__ tpos,
    const int* __restrict__ meta, float* __restrict__ out) {
  const int t = blockIdx.x;
  const int c = threadIdx.x * 4;
  const int2 tp = tpos[t];
  const int ea = tp.x >> 13, pa = tp.x & 8191;
  const int eb = tp.y >> 13, pb = tp.y & 8191;
  const bf16* A4 = &P[(size_t)(meta[34 + ea] + pa) * DDIM + c];
  const bf16* B4 = &P[(size_t)(meta[34 + eb] + pb) * DDIM + c];
  float4 o = *(float4*)&out[(size_t)t * DDIM + c];
  o.x += (float)A4[0] + (float)B4[0];
  o.y += (float)A4[1] + (float)B4[1];
  o.z += (float)A4[2] + (float)B4[2];
  o.w += (float)A4[3] + (float)B4[3];
  *(float4*)&out[(size_t)t * DDIM + c] = o;
}

extern "C" void kernel_launch(void* const* d_in, const int* in_sizes, int n_in,
                              void* d_out, int out_size, void* d_ws,
                              size_t ws_size, hipStream_t stream) {
  const float* x = (const float*)d_in[0];
  const float* spec_w1 = (const float*)d_in[1];
  const float* spec_b1 = (const float*)d_in[2];
  const float* spec_w2 = (const float*)d_in[3];
  const float* spec_b2 = (const float*)d_in[4];
  const float* spec_rw = (const float*)d_in[5];
  const float* spec_rb = (const float*)d_in[6];
  const float* shr_w1 = (const float*)d_in[7];
  const float* shr_b1 = (const float*)d_in[8];
  const float* shr_w2 = (const float*)d_in[9];
  const float* shr_b2 = (const float*)d_in[10];
  const float* shr_rw = (const float*)d_in[11];
  const float* shr_rb = (const float*)d_in[12];
  float* out = (float*)d_out;

  char* ws = (char*)d_ws;
  const size_t DH = (size_t)DDIM * HDIM;
  const size_t OFF_W1 = 16777216;            // xb 16 MB
  const size_t OFF_W2 = OFF_W1 + 50331648;   // w1t 48 MB (P reuses this!)
  const size_t OFF_GATE = OFF_W2 + 50331648; // w2t 48 MB
  const size_t OFF_AUX = OFF_GATE + 262144;
  const size_t OFF_META = OFF_AUX + 256;
  const size_t OFF_LIST = OFF_META + 256;
  const size_t OFF_T2 = OFF_LIST + 131072;
  const size_t OFF_P4 = OFF_T2 + 32768;
  const size_t OFF_TPOS = OFF_P4 + 131072 + 1024;
  const size_t OFF_H = OFF_TPOS + 65536;
  bf16* xb = (bf16*)ws;
  bf16* w1t = (bf16*)(ws + OFF_W1);
  bf16* w2t = (bf16*)(ws + OFF_W2);
  float* gate = (float*)(ws + OFF_GATE);
  float* auxg = (float*)(ws + OFF_AUX);
  int* meta = (int*)(ws + OFF_META);
  int* lists = (int*)(ws + OFF_LIST);
  int* top2 = (int*)(ws + OFF_T2);
  float4* probs4 = (float4*)(ws + OFF_P4);
  int2* tpos = (int2*)(ws + OFF_TPOS);
  bf16* h = (bf16*)(ws + OFF_H);
  // P (spec gated partials, <=17408 x 1024 bf16 = 35.7 MB) reuses the w1t
  // region: w1 weights are dead once the last g1 dispatch has run.
  bf16* P = w1t;

  hipMemsetAsync(lists, 0xFF, 4 * 8192 * 4, stream);

  conv_router<<<T_TOK / 4, 256, 0, stream>>>(x, xb, spec_rw, spec_rb, shr_rw,
                                             shr_rb, gate, probs4, top2);
  scan_build<<<1, 1024, 0, stream>>>(top2, probs4, meta, lists, tpos, auxg);

  transpose_convert6<<<dim3(HDIM / 32, DDIM / 32, 6), 256, 0, stream>>>(
      spec_w1, shr_w1, w1t, DDIM, HDIM);
  transpose_convert6<<<dim3(DDIM / 32, HDIM / 32, 6), 256, 0, stream>>>(
      spec_w2, shr_w2, w2t, HDIM, DDIM);

  // 1) merged shared g1: h_shr [8192,8192]
  g8<0><<<1024, 512, 0, stream>>>(xb, w1t + 4 * DH, shr_b1, h, 8192,
                                  8, 16, meta, lists);
  // 2) shared g2s read h_shr with lda=8192 (e0 '=', e1 '+=')
  g2k<0><<<256, 512, 0, stream>>>(h, 8192, w2t + 4 * DH, shr_b2, out,
                                  gate, 4);
  g2k<1><<<256, 512, 0, stream>>>(h + 4096, 8192, w2t + 5 * DH,
                                  shr_b2 + 1024, out, gate, 5);
  // 3) batched spec g1 (packed h; w1t consumed here -> P may reuse it after)
  g8<1><<<2048, 512, 0, stream>>>(xb, w1t, spec_b1, h, 4096,
                                  0, 8, meta, lists);
  // 4) batched spec g2 -> gated partials P ('=', no races), then reduce
  g2sp<<<1024, 512, 0, stream>>>(h, w2t, spec_b2, P, gate, meta, lists);
  reduce_spec<<<T_TOK, 256, 0, stream>>>(P, tpos, meta, out);

  aux_finalize<<<1, 1, 0, stream>>>(auxg, out + (size_t)T_TOK * DDIM);
}